// Round 1
// baseline (1234.868 us; speedup 1.0000x reference)
//
#include <hip/hip_runtime.h>

#define D_DIM 128
#define K_DIM 1024
#define BM 64
#define BN 64

// ---------------------------------------------------------------------------
// prep: transpose centroids C[1024][128] -> Ct[128][1024], compute c2[k]=|c_k|^2
// ---------------------------------------------------------------------------
__global__ __launch_bounds__(256) void prep_kernel(const float* __restrict__ C,
                                                   float* __restrict__ Ct,
                                                   float* __restrict__ c2) {
    int k = blockIdx.x * blockDim.x + threadIdx.x;
    if (k >= K_DIM) return;
    float s0 = 0.f, s1 = 0.f, s2 = 0.f, s3 = 0.f;
    for (int d = 0; d < D_DIM; d += 4) {
        float v0 = C[k * D_DIM + d + 0];
        float v1 = C[k * D_DIM + d + 1];
        float v2 = C[k * D_DIM + d + 2];
        float v3 = C[k * D_DIM + d + 3];
        s0 = fmaf(v0, v0, s0);
        s1 = fmaf(v1, v1, s1);
        s2 = fmaf(v2, v2, s2);
        s3 = fmaf(v3, v3, s3);
        Ct[(d + 0) * K_DIM + k] = v0;
        Ct[(d + 1) * K_DIM + k] = v1;
        Ct[(d + 2) * K_DIM + k] = v2;
        Ct[(d + 3) * K_DIM + k] = v3;
    }
    c2[k] = (s0 + s1) + (s2 + s3);
}

// ---------------------------------------------------------------------------
// fused: distances + argmin + online logsumexp + mean-loss
// block = 256 threads (16x16), tile = 64 rows x 64 cols per chunk, 16 chunks
// ---------------------------------------------------------------------------
__global__ __launch_bounds__(256, 2) void fused_kernel(const float* __restrict__ E,
                                                       const float* __restrict__ Ct,
                                                       const float* __restrict__ c2,
                                                       float* __restrict__ out,
                                                       int N) {
    __shared__ float Elds[D_DIM][BM];   // 32 KB, transposed [d][row]
    __shared__ float Clds[D_DIM][BN];   // 32 KB, transposed [d][col]
    __shared__ float e2s[BM];
    __shared__ float c2s[BN];

    const int tid = threadIdx.x;
    const int tx = tid & 15;    // col group
    const int ty = tid >> 4;    // row group
    const int row0 = blockIdx.x * BM;

    // ---- stage E tile (transpose into LDS) ----
    {
        const float4* E4 = (const float4*)(E + (size_t)row0 * D_DIM);
        #pragma unroll
        for (int it = 0; it < 8; ++it) {
            int idx = it * 256 + tid;      // 0..2047
            int r   = idx >> 5;            // 0..63
            int c4  = idx & 31;            // 0..31
            float4 v = E4[r * 32 + c4];
            int d = c4 * 4;
            Elds[d + 0][r] = v.x;
            Elds[d + 1][r] = v.y;
            Elds[d + 2][r] = v.z;
            Elds[d + 3][r] = v.w;
        }
    }
    __syncthreads();
    if (tid < BM) {
        float s = 0.f;
        #pragma unroll 8
        for (int d = 0; d < D_DIM; ++d) {
            float v = Elds[d][tid];
            s = fmaf(v, v, s);
        }
        e2s[tid] = s;
    }

    // online state per owned row: min dist, argmin, sum exp(m - d)
    float mrow[4] = {1e30f, 1e30f, 1e30f, 1e30f};
    float srow[4] = {0.f, 0.f, 0.f, 0.f};
    int   irow[4] = {0, 0, 0, 0};

    const float4* Ct4 = (const float4*)Ct;

    for (int j = 0; j < K_DIM / BN; ++j) {
        __syncthreads();   // previous chunk's reads of Clds done (covers E/e2s on j=0)
        #pragma unroll
        for (int it = 0; it < 8; ++it) {
            int idx = it * 256 + tid;     // 0..2047
            int d   = idx >> 4;           // 0..127
            int c4  = idx & 15;           // 0..15
            float4 v = Ct4[d * (K_DIM / 4) + j * (BN / 4) + c4];
            *(float4*)&Clds[d][c4 * 4] = v;
        }
        if (tid < BN / 4) {
            *(float4*)&c2s[tid * 4] = *(const float4*)&c2[j * BN + tid * 4];
        }
        __syncthreads();

        float acc[4][4] = {{0.f}};
        #pragma unroll 8
        for (int d = 0; d < D_DIM; ++d) {
            float4 a = *(const float4*)&Elds[d][ty * 4];
            float4 b = *(const float4*)&Clds[d][tx * 4];
            acc[0][0] = fmaf(a.x, b.x, acc[0][0]);
            acc[0][1] = fmaf(a.x, b.y, acc[0][1]);
            acc[0][2] = fmaf(a.x, b.z, acc[0][2]);
            acc[0][3] = fmaf(a.x, b.w, acc[0][3]);
            acc[1][0] = fmaf(a.y, b.x, acc[1][0]);
            acc[1][1] = fmaf(a.y, b.y, acc[1][1]);
            acc[1][2] = fmaf(a.y, b.z, acc[1][2]);
            acc[1][3] = fmaf(a.y, b.w, acc[1][3]);
            acc[2][0] = fmaf(a.z, b.x, acc[2][0]);
            acc[2][1] = fmaf(a.z, b.y, acc[2][1]);
            acc[2][2] = fmaf(a.z, b.z, acc[2][2]);
            acc[2][3] = fmaf(a.z, b.w, acc[2][3]);
            acc[3][0] = fmaf(a.w, b.x, acc[3][0]);
            acc[3][1] = fmaf(a.w, b.y, acc[3][1]);
            acc[3][2] = fmaf(a.w, b.z, acc[3][2]);
            acc[3][3] = fmaf(a.w, b.w, acc[3][3]);
        }

        // fused epilogue: d2 = (e2+c2) - 2*dot (matches np rounding: 2*dot exact)
        #pragma unroll
        for (int r = 0; r < 4; ++r) {
            float e2v = e2s[ty * 4 + r];
            #pragma unroll
            for (int c = 0; c < 4; ++c) {
                int k = j * BN + tx * 4 + c;   // increasing k within thread
                float d2   = (e2v + c2s[tx * 4 + c]) - 2.0f * acc[r][c];
                float dist = sqrtf(fmaxf(d2, 0.f));
                float om = mrow[r];
                float nm = fminf(om, dist);
                if (dist < om) irow[r] = k;    // strict <: first occurrence wins
                srow[r] = srow[r] * __expf(nm - om) + __expf(nm - dist);
                mrow[r] = nm;
            }
        }
    }

    // ---- cross-thread reduction over the 16 col-groups, via LDS (reuse Elds) ----
    __syncthreads();
    float* Rm = &Elds[0][0];           // [64][16]
    float* Rs = Rm + BM * 16;          // [64][16]
    int*   Ri = (int*)(Rm + 2 * BM * 16);
    #pragma unroll
    for (int r = 0; r < 4; ++r) {
        int row = ty * 4 + r;
        Rm[row * 16 + tx] = mrow[r];
        Rs[row * 16 + tx] = srow[r];
        Ri[row * 16 + tx] = irow[r];
    }
    __syncthreads();
    if (tid < BM) {   // exactly wave 0
        int row = tid;
        float mg = 1e30f;
        int   ig = 0x7fffffff;
        #pragma unroll
        for (int t = 0; t < 16; ++t) {
            float mv = Rm[row * 16 + t];
            int   iv = Ri[row * 16 + t];
            if (mv < mg || (mv == mg && iv < ig)) { mg = mv; ig = iv; }
        }
        float S = 0.f;
        #pragma unroll
        for (int t = 0; t < 16; ++t) {
            S += Rs[row * 16 + t] * __expf(mg - Rm[row * 16 + t]);
        }
        float lossr = logf(S);          // lse - target = log sum exp(min - d)
        out[1 + row0 + row] = (float)ig;

        // wave-level sum (64 lanes), then one atomic per block
        float v = lossr;
        #pragma unroll
        for (int off = 32; off > 0; off >>= 1) v += __shfl_down(v, off);
        if (tid == 0) atomicAdd(out, v / (float)N);
    }
}

extern "C" void kernel_launch(void* const* d_in, const int* in_sizes, int n_in,
                              void* d_out, int out_size, void* d_ws, size_t ws_size,
                              hipStream_t stream) {
    const float* E = (const float*)d_in[0];
    const float* C = (const float*)d_in[1];
    float* out = (float*)d_out;
    const int N = in_sizes[0] / D_DIM;    // 262144

    float* Ct = (float*)d_ws;             // 128*1024 f32
    float* c2 = Ct + D_DIM * K_DIM;       // 1024 f32

    hipMemsetAsync(d_out, 0, sizeof(float), stream);   // loss accumulator
    prep_kernel<<<dim3(K_DIM / 256), dim3(256), 0, stream>>>(C, Ct, c2);
    fused_kernel<<<dim3(N / BM), dim3(256), 0, stream>>>(E, Ct, c2, out, N);
}

// Round 2
// 881.446 us; speedup vs baseline: 1.4010x; 1.4010x over previous
//
#include <hip/hip_runtime.h>
#include <stdint.h>

#define D_DIM 128
#define K_DIM 1024
#define BM 128
#define N_TOTAL 262144
#define TAU 0.1f
#define MAXF 8192

typedef __attribute__((ext_vector_type(8))) short short8;
typedef __attribute__((ext_vector_type(4))) float f32x4;

__device__ __forceinline__ unsigned short f2bf(float f) {
    union { float f; uint32_t u; } v; v.f = f;
    uint32_t r = v.u + 0x7fffu + ((v.u >> 16) & 1u);
    return (unsigned short)(r >> 16);
}
__device__ __forceinline__ float bf2f(unsigned short h) {
    union { float f; uint32_t u; } v; v.u = ((uint32_t)h) << 16;
    return v.f;
}

// ---------------------------------------------------------------------------
// prep_c: C[1024][128] fp32 -> B-frag-layout bf16 hi/lo + c2[k]
// B-frag (16x16x32): element B[n=lane&15][k=(lane>>4)*8+j]
// Cfrag[half][ntg(64)][ds(4)][lane(64)][j(8)]
// ---------------------------------------------------------------------------
__global__ void prep_c_kernel(const float* __restrict__ C,
                              unsigned short* __restrict__ Cfrag,
                              float* __restrict__ c2) {
    int col = blockIdx.x * blockDim.x + threadIdx.x;
    if (col >= K_DIM) return;
    float s = 0.f;
    int ntg = col >> 4;
    int cl = col & 15;
    for (int d = 0; d < D_DIM; ++d) {
        float v = C[(size_t)col * D_DIM + d];
        s = fmaf(v, v, s);
        unsigned short hi = f2bf(v);
        unsigned short lo = f2bf(v - bf2f(hi));
        int ds = d >> 5;
        int lane = (((d >> 3) & 3) << 4) | cl;
        int j = d & 7;
        size_t idx = ((((size_t)ntg * 4 + ds) * 64 + lane) * 8 + j);
        Cfrag[idx] = hi;
        Cfrag[131072 + idx] = lo;
    }
    c2[col] = s;
}

// ---------------------------------------------------------------------------
// fused: bf16x3 MFMA distances + argmin/2nd-min + sum exp(-d) + loss
// block 256 thr = 4 waves (2x2 of 64x64 wave-tiles), block tile 128x128 cols/chunk
// ---------------------------------------------------------------------------
__global__ __launch_bounds__(256, 2) void fused_mfma_kernel(
        const float* __restrict__ E,
        const unsigned short* __restrict__ Cfrag,
        const float* __restrict__ c2g,
        float* __restrict__ out,
        int* __restrict__ fcnt,
        int* __restrict__ flist)
{
    // E frag LDS: seg=[half(2)][mt(8)][ds(4)], 528 ushorts/seg (1024B + 32B pad)
    __shared__ unsigned short Elds[64 * 528];   // 66 KB
    __shared__ float c2s[K_DIM];                // 4 KB
    __shared__ float e2s[BM];                   // 512 B
    __shared__ float4 mrg[BM * 2];              // 4 KB

    const int tid = threadIdx.x;
    const int lane = tid & 63;
    const int w = tid >> 6;
    const int Rh = w >> 1;       // row half of block tile
    const int Nh = w & 1;        // col half of k-chunk
    const int q = lane >> 4;
    const int mcol = lane & 15;
    const int row0 = blockIdx.x * BM;

    if (tid < BM) e2s[tid] = 0.f;
    for (int i = tid; i < K_DIM; i += 256) c2s[i] = c2g[i];
    __syncthreads();

    // ---- stage E tile: fp32 -> bf16 hi/lo into frag layout; accumulate e2 ----
    {
        const float4* E4 = (const float4*)(E + (size_t)row0 * D_DIM);
        for (int it = 0; it < 16; ++it) {
            int chunk = it * 256 + tid;      // 0..4095
            int r = chunk >> 5;              // row 0..127
            int dq = chunk & 31;             // float4 idx, d0 = dq*4
            float4 v = E4[chunk];
            float p = fmaf(v.x, v.x, fmaf(v.y, v.y, fmaf(v.z, v.z, v.w * v.w)));
            atomicAdd(&e2s[r], p);
            unsigned short h0 = f2bf(v.x), h1 = f2bf(v.y), h2 = f2bf(v.z), h3 = f2bf(v.w);
            unsigned short l0 = f2bf(v.x - bf2f(h0)), l1 = f2bf(v.y - bf2f(h1));
            unsigned short l2 = f2bf(v.z - bf2f(h2)), l3 = f2bf(v.w - bf2f(h3));
            int d0 = dq << 2;
            int mt = r >> 4;
            int ds = d0 >> 5;
            int lane_slot = (((d0 >> 3) & 3) << 4) | (r & 15);
            int jb = d0 & 7;                 // 0 or 4
            int segh = (mt * 4 + ds) * 528 + lane_slot * 8 + jb;
            uint2 hv = make_uint2((uint32_t)h0 | ((uint32_t)h1 << 16),
                                  (uint32_t)h2 | ((uint32_t)h3 << 16));
            uint2 lv = make_uint2((uint32_t)l0 | ((uint32_t)l1 << 16),
                                  (uint32_t)l2 | ((uint32_t)l3 << 16));
            *(uint2*)&Elds[segh] = hv;
            *(uint2*)&Elds[32 * 528 + segh] = lv;
        }
    }
    __syncthreads();

    // per-lane e2 for the 16 owned rows: slot s=(mi*4+r) -> row (Rh*4+mi)*16 + q*4 + r
    float e2r[16];
    #pragma unroll
    for (int s = 0; s < 16; ++s)
        e2r[s] = e2s[(Rh * 4 + (s >> 2)) * 16 + q * 4 + (s & 3)];

    float m1v[16], m2v[16], i1v[16], sv[16];
    #pragma unroll
    for (int s = 0; s < 16; ++s) { m1v[s] = 1e30f; m2v[s] = 1e30f; i1v[s] = 0.f; sv[s] = 0.f; }

    const short8* Bfrag = (const short8*)Cfrag;   // hi at [0], lo at +16384 (short8 units)

    #pragma unroll 1
    for (int kc = 0; kc < 8; ++kc) {
        f32x4 acc[4][4];
        #pragma unroll
        for (int i = 0; i < 4; ++i)
            #pragma unroll
            for (int j = 0; j < 4; ++j)
                acc[i][j] = (f32x4){0.f, 0.f, 0.f, 0.f};

        #pragma unroll
        for (int ds = 0; ds < 4; ++ds) {
            short8 ah[4], al[4];
            #pragma unroll
            for (int mi = 0; mi < 4; ++mi) {
                int seg = ((Rh * 4 + mi) * 4 + ds) * 528 + lane * 8;
                ah[mi] = *(const short8*)&Elds[seg];
                al[mi] = *(const short8*)&Elds[32 * 528 + seg];
            }
            #pragma unroll
            for (int ni = 0; ni < 4; ++ni) {
                int ntg = kc * 8 + Nh * 4 + ni;
                size_t bidx = ((size_t)ntg * 4 + ds) * 64 + lane;
                short8 bh = Bfrag[bidx];
                short8 bl = Bfrag[16384 + bidx];
                #pragma unroll
                for (int mi = 0; mi < 4; ++mi) {
                    acc[mi][ni] = __builtin_amdgcn_mfma_f32_16x16x32_bf16(al[mi], bh, acc[mi][ni], 0, 0, 0);
                    acc[mi][ni] = __builtin_amdgcn_mfma_f32_16x16x32_bf16(ah[mi], bl, acc[mi][ni], 0, 0, 0);
                    acc[mi][ni] = __builtin_amdgcn_mfma_f32_16x16x32_bf16(ah[mi], bh, acc[mi][ni], 0, 0, 0);
                }
            }
        }
        // fused epilogue for this k-chunk (no barriers anywhere in the kc loop)
        #pragma unroll
        for (int ni = 0; ni < 4; ++ni) {
            int kidx = kc * 128 + Nh * 64 + ni * 16 + mcol;
            float c2v = c2s[kidx];
            float kf = (float)kidx;
            #pragma unroll
            for (int mi = 0; mi < 4; ++mi) {
                #pragma unroll
                for (int r = 0; r < 4; ++r) {
                    int s = mi * 4 + r;
                    float d2 = fmaf(-2.f, acc[mi][ni][r], e2r[s] + c2v);
                    d2 = fmaxf(d2, 0.f);
                    float dist = __builtin_amdgcn_sqrtf(d2);
                    sv[s] += __expf(-dist);
                    bool c1 = d2 < m1v[s];
                    bool c2b = d2 < m2v[s];
                    m2v[s] = c1 ? m1v[s] : (c2b ? d2 : m2v[s]);
                    i1v[s] = c1 ? kf : i1v[s];
                    m1v[s] = c1 ? d2 : m1v[s];
                }
            }
        }
    }

    // ---- merge across the 16 lanes sharing q (cols) ----
    #pragma unroll
    for (int s = 0; s < 16; ++s) {
        #pragma unroll
        for (int off = 1; off < 16; off <<= 1) {
            float om1 = __shfl_xor(m1v[s], off);
            float om2 = __shfl_xor(m2v[s], off);
            float oi1 = __shfl_xor(i1v[s], off);
            float osv = __shfl_xor(sv[s], off);
            float lo = fminf(m1v[s], om1);
            float hi = fmaxf(m1v[s], om1);
            m2v[s] = fminf(hi, fminf(m2v[s], om2));
            bool take = (om1 < m1v[s]) || ((om1 == m1v[s]) && (oi1 < i1v[s]));
            i1v[s] = take ? oi1 : i1v[s];
            m1v[s] = lo;
            sv[s] += osv;
        }
    }
    if (mcol == 0) {
        #pragma unroll
        for (int s = 0; s < 16; ++s) {
            int row = (Rh * 4 + (s >> 2)) * 16 + q * 4 + (s & 3);
            mrg[row * 2 + Nh] = make_float4(m1v[s], m2v[s], i1v[s], sv[s]);
        }
    }
    __syncthreads();

    // ---- final per-row merge across the two col-halves; outputs ----
    if (tid < BM) {
        float4 a = mrg[tid * 2 + 0];
        float4 b = mrg[tid * 2 + 1];
        float lo = fminf(a.x, b.x);
        float hi = fmaxf(a.x, b.x);
        float m2 = fminf(hi, fminf(a.y, b.y));
        bool take = (b.x < a.x) || ((b.x == a.x) && (b.z < a.z));
        float i1 = take ? b.z : a.z;
        float m1 = lo;
        float ss = a.w + b.w;
        float lossr = logf(ss) + sqrtf(m1);   // lse - target
        out[1 + row0 + tid] = i1;
        if (m2 - m1 < TAU) {
            int idx = atomicAdd(fcnt, 1);
            if (idx < MAXF) flist[idx] = row0 + tid;
        }
        e2s[tid] = lossr;   // reuse as loss buffer
    }
    __syncthreads();
    if (tid < 64) {
        float v = e2s[tid] + e2s[tid + 64];
        #pragma unroll
        for (int off = 32; off > 0; off >>= 1) v += __shfl_down(v, off);
        if (tid == 0) atomicAdd(out, v * (1.0f / (float)N_TOTAL));
    }
}

// ---------------------------------------------------------------------------
// refine: exact fp32 recompute (precise sqrt, first-occurrence argmin) for
// rows whose bf16x3 top-2 gap < TAU. 4 rows per block.
// ---------------------------------------------------------------------------
__global__ void refine_kernel(const float* __restrict__ E,
                              const float* __restrict__ C,
                              const float* __restrict__ c2g,
                              const int* __restrict__ fcnt,
                              const int* __restrict__ flist,
                              float* __restrict__ out) {
    int cnt = *fcnt;
    if (cnt > MAXF) cnt = MAXF;
    int base = blockIdx.x * 4;
    if (base >= cnt) return;
    int nr = cnt - base;
    if (nr > 4) nr = 4;

    __shared__ float Er[4][D_DIM];
    __shared__ float e2r_[4];
    __shared__ float2 red[256];

    const int tid = threadIdx.x;
    int rows[4];
    #pragma unroll
    for (int r = 0; r < 4; ++r) {
        int rr = r < nr ? r : (nr - 1);
        rows[r] = flist[base + rr];
    }
    for (int i = tid; i < 4 * D_DIM; i += 256) {
        int rr = i >> 7;
        int dd = i & 127;
        Er[rr][dd] = E[(size_t)rows[rr] * D_DIM + dd];
    }
    __syncthreads();
    if (tid < 4) {
        float s = 0.f;
        for (int d = 0; d < D_DIM; ++d) s = fmaf(Er[tid][d], Er[tid][d], s);
        e2r_[tid] = s;
    }
    __syncthreads();

    float bm[4] = {1e30f, 1e30f, 1e30f, 1e30f};
    float bk[4] = {0.f, 0.f, 0.f, 0.f};
    for (int ii = 0; ii < 4; ++ii) {
        int k = ii * 256 + tid;
        float dot0 = 0.f, dot1 = 0.f, dot2 = 0.f, dot3 = 0.f;
        const float4* C4 = (const float4*)(C + (size_t)k * D_DIM);
        for (int dq = 0; dq < 32; ++dq) {
            float4 cv = C4[dq];
            int d0 = dq * 4;
            dot0 = fmaf(Er[0][d0], cv.x, fmaf(Er[0][d0 + 1], cv.y, fmaf(Er[0][d0 + 2], cv.z, fmaf(Er[0][d0 + 3], cv.w, dot0))));
            dot1 = fmaf(Er[1][d0], cv.x, fmaf(Er[1][d0 + 1], cv.y, fmaf(Er[1][d0 + 2], cv.z, fmaf(Er[1][d0 + 3], cv.w, dot1))));
            dot2 = fmaf(Er[2][d0], cv.x, fmaf(Er[2][d0 + 1], cv.y, fmaf(Er[2][d0 + 2], cv.z, fmaf(Er[2][d0 + 3], cv.w, dot2))));
            dot3 = fmaf(Er[3][d0], cv.x, fmaf(Er[3][d0 + 1], cv.y, fmaf(Er[3][d0 + 2], cv.z, fmaf(Er[3][d0 + 3], cv.w, dot3))));
        }
        float c2v = c2g[k];
        float dd[4];
        dd[0] = dot0; dd[1] = dot1; dd[2] = dot2; dd[3] = dot3;
        #pragma unroll
        for (int r = 0; r < 4; ++r) {
            float d2 = (e2r_[r] + c2v) - 2.f * dd[r];
            float dist = sqrtf(fmaxf(d2, 0.f));
            if (dist < bm[r]) { bm[r] = dist; bk[r] = (float)k; }
        }
    }
    for (int r = 0; r < nr; ++r) {
        red[tid] = make_float2(bm[r], bk[r]);
        __syncthreads();
        for (int off = 128; off > 0; off >>= 1) {
            if (tid < off) {
                float2 o = red[tid + off];
                float2 m = red[tid];
                if (o.x < m.x || (o.x == m.x && o.y < m.y)) red[tid] = o;
            }
            __syncthreads();
        }
        if (tid == 0) out[1 + rows[r]] = red[0].y;
        __syncthreads();
    }
}

extern "C" void kernel_launch(void* const* d_in, const int* in_sizes, int n_in,
                              void* d_out, int out_size, void* d_ws, size_t ws_size,
                              hipStream_t stream) {
    const float* E = (const float*)d_in[0];
    const float* C = (const float*)d_in[1];
    float* out = (float*)d_out;

    unsigned short* Cfrag = (unsigned short*)d_ws;                 // 512 KB
    float* c2 = (float*)((char*)d_ws + 524288);                    // 4 KB
    int* fcnt = (int*)((char*)d_ws + 524288 + 4096);               // 4 B
    int* flist = fcnt + 1;                                         // MAXF ints

    hipMemsetAsync(d_out, 0, sizeof(float), stream);   // loss accumulator
    hipMemsetAsync(fcnt, 0, sizeof(int), stream);      // refinement counter

    prep_c_kernel<<<dim3(K_DIM / 256), dim3(256), 0, stream>>>(C, Cfrag, c2);
    fused_mfma_kernel<<<dim3(N_TOTAL / BM), dim3(256), 0, stream>>>(E, Cfrag, c2, out, fcnt, flist);
    refine_kernel<<<dim3(MAXF / 4), dim3(256), 0, stream>>>(E, C, c2, fcnt, flist, out);
}

// Round 3
// 871.434 us; speedup vs baseline: 1.4171x; 1.0115x over previous
//
#include <hip/hip_runtime.h>
#include <stdint.h>

#define D_DIM 128
#define K_DIM 1024
#define BM 64
#define N_TOTAL 262144
#define TAU 0.1f
#define MAXF 8192

typedef __attribute__((ext_vector_type(8))) short short8;
typedef __attribute__((ext_vector_type(4))) float f32x4;

__device__ __forceinline__ unsigned short f2bf(float f) {
    union { float f; uint32_t u; } v; v.f = f;
    uint32_t r = v.u + 0x7fffu + ((v.u >> 16) & 1u);
    return (unsigned short)(r >> 16);
}
__device__ __forceinline__ float bf2f(unsigned short h) {
    union { float f; uint32_t u; } v; v.u = ((uint32_t)h) << 16;
    return v.f;
}

// ---------------------------------------------------------------------------
// prep_c2: c2[k]=|c_k|^2, rounding bit-identical to R2 (s0..s3 lane chains)
// ---------------------------------------------------------------------------
__global__ void prep_c2_kernel(const float* __restrict__ C,
                               float* __restrict__ c2) {
    int col = blockIdx.x * blockDim.x + threadIdx.x;
    if (col >= K_DIM) return;
    const float4* C4 = (const float4*)(C + (size_t)col * D_DIM);
    float s0 = 0.f, s1 = 0.f, s2 = 0.f, s3 = 0.f;
    #pragma unroll
    for (int dq = 0; dq < 32; ++dq) {
        float4 v = C4[dq];
        s0 = fmaf(v.x, v.x, s0);
        s1 = fmaf(v.y, v.y, s1);
        s2 = fmaf(v.z, v.z, s2);
        s3 = fmaf(v.w, v.w, s3);
    }
    c2[col] = (s0 + s1) + (s2 + s3);
}

// ---------------------------------------------------------------------------
// prep_frag: C[1024][128] fp32 -> B-frag-layout bf16 hi/lo (parallel, coalesced)
// one thread per (col, d-quad): 32768 items / 256 = 128 blocks
// ---------------------------------------------------------------------------
__global__ void prep_frag_kernel(const float* __restrict__ C,
                                 unsigned short* __restrict__ Cfrag) {
    int g = blockIdx.x * blockDim.x + threadIdx.x;   // 0..32767
    int col = g >> 5;
    int dq = g & 31;
    float4 v = ((const float4*)C)[g];
    unsigned short h0 = f2bf(v.x), h1 = f2bf(v.y), h2 = f2bf(v.z), h3 = f2bf(v.w);
    unsigned short l0 = f2bf(v.x - bf2f(h0)), l1 = f2bf(v.y - bf2f(h1));
    unsigned short l2 = f2bf(v.z - bf2f(h2)), l3 = f2bf(v.w - bf2f(h3));
    int ntg = col >> 4;
    int cl = col & 15;
    int d0 = dq << 2;
    int ds = d0 >> 5;
    int lane = (((d0 >> 3) & 3) << 4) | cl;
    int jb = d0 & 7;                                  // 0 or 4
    size_t idx = (((size_t)(ntg * 4 + ds) * 64 + lane) * 8 + jb);
    uint2 hv = make_uint2((uint32_t)h0 | ((uint32_t)h1 << 16),
                          (uint32_t)h2 | ((uint32_t)h3 << 16));
    uint2 lv = make_uint2((uint32_t)l0 | ((uint32_t)l1 << 16),
                          (uint32_t)l2 | ((uint32_t)l3 << 16));
    *(uint2*)&Cfrag[idx] = hv;
    *(uint2*)&Cfrag[131072 + idx] = lv;
}

// ---------------------------------------------------------------------------
// fused: bf16x3 MFMA distances + argmin/2nd-min + sum exp(-d) + loss
// block 256 thr = 4 waves; wave tile 32 rows x 64 cols per kc chunk
// block tile 64 rows x 128 cols/chunk, 8 chunks. ~111 VGPRs -> no spill @128.
// ---------------------------------------------------------------------------
__global__ __launch_bounds__(256, 4) void fused_mfma_kernel(
        const float* __restrict__ E,
        const unsigned short* __restrict__ Cfrag,
        const float* __restrict__ c2g,
        float* __restrict__ out,
        int* __restrict__ fcnt,
        int* __restrict__ flist)
{
    // E frag LDS: 32 segs (16 hi + 16 lo) of 528 ushorts (1KB + 32B pad)
    __shared__ unsigned short Elds[32 * 528];   // 33 KB
    __shared__ float c2s[K_DIM];                // 4 KB
    __shared__ float e2s[BM];                   // 256 B
    __shared__ float4 mrg[BM * 2];              // 2 KB

    const int tid = threadIdx.x;
    const int lane = tid & 63;
    const int w = tid >> 6;
    const int Rh = w >> 1;       // row half (32 rows each)
    const int Nh = w & 1;        // col half of each 128-col chunk
    const int q = lane >> 4;
    const int mcol = lane & 15;
    const int row0 = blockIdx.x * BM;

    if (tid < BM) e2s[tid] = 0.f;
    for (int i = tid; i < K_DIM; i += 256) c2s[i] = c2g[i];
    __syncthreads();

    // ---- stage E tile: fp32 -> bf16 hi/lo frag layout; accumulate e2 ----
    {
        const float4* E4 = (const float4*)(E + (size_t)row0 * D_DIM);
        #pragma unroll
        for (int it = 0; it < 8; ++it) {
            int chunk = it * 256 + tid;      // 0..2047
            int r = chunk >> 5;              // row 0..63
            int dq = chunk & 31;
            float4 v = E4[chunk];
            float p = fmaf(v.x, v.x, fmaf(v.y, v.y, fmaf(v.z, v.z, v.w * v.w)));
            atomicAdd(&e2s[r], p);
            unsigned short h0 = f2bf(v.x), h1 = f2bf(v.y), h2 = f2bf(v.z), h3 = f2bf(v.w);
            unsigned short l0 = f2bf(v.x - bf2f(h0)), l1 = f2bf(v.y - bf2f(h1));
            unsigned short l2 = f2bf(v.z - bf2f(h2)), l3 = f2bf(v.w - bf2f(h3));
            int d0 = dq << 2;
            int mt = r >> 4;                 // 0..3
            int ds = d0 >> 5;
            int lane_slot = (((d0 >> 3) & 3) << 4) | (r & 15);
            int jb = d0 & 7;
            int segh = (mt * 4 + ds) * 528 + lane_slot * 8 + jb;
            uint2 hv = make_uint2((uint32_t)h0 | ((uint32_t)h1 << 16),
                                  (uint32_t)h2 | ((uint32_t)h3 << 16));
            uint2 lv = make_uint2((uint32_t)l0 | ((uint32_t)l1 << 16),
                                  (uint32_t)l2 | ((uint32_t)l3 << 16));
            *(uint2*)&Elds[segh] = hv;
            *(uint2*)&Elds[16 * 528 + segh] = lv;
        }
    }
    __syncthreads();

    // per-lane e2 for the 8 owned rows: slot s=mi*4+r -> row (Rh*2+mi)*16+q*4+r
    float e2r[8];
    #pragma unroll
    for (int s = 0; s < 8; ++s)
        e2r[s] = e2s[(Rh * 2 + (s >> 2)) * 16 + q * 4 + (s & 3)];

    float m1v[8], m2v[8], i1v[8], sv[8];
    #pragma unroll
    for (int s = 0; s < 8; ++s) { m1v[s] = 1e30f; m2v[s] = 1e30f; i1v[s] = 0.f; sv[s] = 0.f; }

    const short8* Bfrag = (const short8*)Cfrag;   // hi at [0], lo at +16384 (short8 units)

    #pragma unroll 1
    for (int kc = 0; kc < 8; ++kc) {
        f32x4 acc[2][4];
        #pragma unroll
        for (int i = 0; i < 2; ++i)
            #pragma unroll
            for (int j = 0; j < 4; ++j)
                acc[i][j] = (f32x4){0.f, 0.f, 0.f, 0.f};

        #pragma unroll
        for (int ds = 0; ds < 4; ++ds) {
            short8 ah[2], al[2];
            #pragma unroll
            for (int mi = 0; mi < 2; ++mi) {
                int seg = ((Rh * 2 + mi) * 4 + ds) * 528 + lane * 8;
                ah[mi] = *(const short8*)&Elds[seg];
                al[mi] = *(const short8*)&Elds[16 * 528 + seg];
            }
            #pragma unroll
            for (int ni = 0; ni < 4; ++ni) {
                int ntg = kc * 8 + Nh * 4 + ni;
                size_t bidx = ((size_t)ntg * 4 + ds) * 64 + lane;
                short8 bh = Bfrag[bidx];
                short8 bl = Bfrag[16384 + bidx];
                #pragma unroll
                for (int mi = 0; mi < 2; ++mi) {
                    acc[mi][ni] = __builtin_amdgcn_mfma_f32_16x16x32_bf16(al[mi], bh, acc[mi][ni], 0, 0, 0);
                    acc[mi][ni] = __builtin_amdgcn_mfma_f32_16x16x32_bf16(ah[mi], bl, acc[mi][ni], 0, 0, 0);
                    acc[mi][ni] = __builtin_amdgcn_mfma_f32_16x16x32_bf16(ah[mi], bh, acc[mi][ni], 0, 0, 0);
                }
            }
        }
        // fused epilogue for this k-chunk (no barriers in the kc loop)
        #pragma unroll
        for (int ni = 0; ni < 4; ++ni) {
            int kidx = kc * 128 + Nh * 64 + ni * 16 + mcol;
            float c2v = c2s[kidx];
            float kf = (float)kidx;
            #pragma unroll
            for (int mi = 0; mi < 2; ++mi) {
                #pragma unroll
                for (int r = 0; r < 4; ++r) {
                    int s = mi * 4 + r;
                    float d2 = fmaf(-2.f, acc[mi][ni][r], e2r[s] + c2v);
                    d2 = fmaxf(d2, 0.f);
                    float dist = __builtin_amdgcn_sqrtf(d2);
                    sv[s] += __expf(-dist);
                    bool c1 = d2 < m1v[s];
                    bool c2b = d2 < m2v[s];
                    m2v[s] = c1 ? m1v[s] : (c2b ? d2 : m2v[s]);
                    i1v[s] = c1 ? kf : i1v[s];
                    m1v[s] = c1 ? d2 : m1v[s];
                }
            }
        }
    }

    // ---- merge across the 16 lanes sharing q (cols) ----
    #pragma unroll
    for (int s = 0; s < 8; ++s) {
        #pragma unroll
        for (int off = 1; off < 16; off <<= 1) {
            float om1 = __shfl_xor(m1v[s], off);
            float om2 = __shfl_xor(m2v[s], off);
            float oi1 = __shfl_xor(i1v[s], off);
            float osv = __shfl_xor(sv[s], off);
            float lo = fminf(m1v[s], om1);
            float hi = fmaxf(m1v[s], om1);
            m2v[s] = fminf(hi, fminf(m2v[s], om2));
            bool take = (om1 < m1v[s]) || ((om1 == m1v[s]) && (oi1 < i1v[s]));
            i1v[s] = take ? oi1 : i1v[s];
            m1v[s] = lo;
            sv[s] += osv;
        }
    }
    if (mcol == 0) {
        #pragma unroll
        for (int s = 0; s < 8; ++s) {
            int row = (Rh * 2 + (s >> 2)) * 16 + q * 4 + (s & 3);
            mrg[row * 2 + Nh] = make_float4(m1v[s], m2v[s], i1v[s], sv[s]);
        }
    }
    __syncthreads();

    // ---- final per-row merge across the two col-halves; outputs ----
    float lossr = 0.f;
    if (tid < BM) {
        float4 a = mrg[tid * 2 + 0];
        float4 b = mrg[tid * 2 + 1];
        float lo = fminf(a.x, b.x);
        float hi = fmaxf(a.x, b.x);
        float m2 = fminf(hi, fminf(a.y, b.y));
        bool take = (b.x < a.x) || ((b.x == a.x) && (b.z < a.z));
        float i1 = take ? b.z : a.z;
        float m1 = lo;
        float ss = a.w + b.w;
        lossr = logf(ss) + sqrtf(m1);   // lse - target
        out[1 + row0 + tid] = i1;
        if (m2 - m1 < TAU) {
            int idx = atomicAdd(fcnt, 1);
            if (idx < MAXF) flist[idx] = row0 + tid;
        }
        // wave 0 only: reduce loss across 64 lanes, one atomic per block
        float v = lossr;
        #pragma unroll
        for (int off = 32; off > 0; off >>= 1) v += __shfl_down(v, off);
        if (tid == 0) atomicAdd(out, v * (1.0f / (float)N_TOTAL));
    }
}

// ---------------------------------------------------------------------------
// refine: exact fp32 recompute (precise sqrt, first-occurrence argmin) for
// rows whose bf16x3 top-2 d^2 gap < TAU. 4 rows per block.
// ---------------------------------------------------------------------------
__global__ void refine_kernel(const float* __restrict__ E,
                              const float* __restrict__ C,
                              const float* __restrict__ c2g,
                              const int* __restrict__ fcnt,
                              const int* __restrict__ flist,
                              float* __restrict__ out) {
    int cnt = *fcnt;
    if (cnt > MAXF) cnt = MAXF;
    int base = blockIdx.x * 4;
    if (base >= cnt) return;
    int nr = cnt - base;
    if (nr > 4) nr = 4;

    __shared__ float Er[4][D_DIM];
    __shared__ float e2r_[4];
    __shared__ float2 red[256];

    const int tid = threadIdx.x;
    int rows[4];
    #pragma unroll
    for (int r = 0; r < 4; ++r) {
        int rr = r < nr ? r : (nr - 1);
        rows[r] = flist[base + rr];
    }
    for (int i = tid; i < 4 * D_DIM; i += 256) {
        int rr = i >> 7;
        int dd = i & 127;
        Er[rr][dd] = E[(size_t)rows[rr] * D_DIM + dd];
    }
    __syncthreads();
    if (tid < 4) {
        float s = 0.f;
        for (int d = 0; d < D_DIM; ++d) s = fmaf(Er[tid][d], Er[tid][d], s);
        e2r_[tid] = s;
    }
    __syncthreads();

    float bm[4] = {1e30f, 1e30f, 1e30f, 1e30f};
    float bk[4] = {0.f, 0.f, 0.f, 0.f};
    for (int ii = 0; ii < 4; ++ii) {
        int k = ii * 256 + tid;
        float dot0 = 0.f, dot1 = 0.f, dot2 = 0.f, dot3 = 0.f;
        const float4* C4 = (const float4*)(C + (size_t)k * D_DIM);
        for (int dq = 0; dq < 32; ++dq) {
            float4 cv = C4[dq];
            int d0 = dq * 4;
            dot0 = fmaf(Er[0][d0], cv.x, fmaf(Er[0][d0 + 1], cv.y, fmaf(Er[0][d0 + 2], cv.z, fmaf(Er[0][d0 + 3], cv.w, dot0))));
            dot1 = fmaf(Er[1][d0], cv.x, fmaf(Er[1][d0 + 1], cv.y, fmaf(Er[1][d0 + 2], cv.z, fmaf(Er[1][d0 + 3], cv.w, dot1))));
            dot2 = fmaf(Er[2][d0], cv.x, fmaf(Er[2][d0 + 1], cv.y, fmaf(Er[2][d0 + 2], cv.z, fmaf(Er[2][d0 + 3], cv.w, dot2))));
            dot3 = fmaf(Er[3][d0], cv.x, fmaf(Er[3][d0 + 1], cv.y, fmaf(Er[3][d0 + 2], cv.z, fmaf(Er[3][d0 + 3], cv.w, dot3))));
        }
        float c2v = c2g[k];
        float dd[4];
        dd[0] = dot0; dd[1] = dot1; dd[2] = dot2; dd[3] = dot3;
        #pragma unroll
        for (int r = 0; r < 4; ++r) {
            float d2 = (e2r_[r] + c2v) - 2.f * dd[r];
            float dist = sqrtf(fmaxf(d2, 0.f));
            if (dist < bm[r]) { bm[r] = dist; bk[r] = (float)k; }
        }
    }
    for (int r = 0; r < nr; ++r) {
        red[tid] = make_float2(bm[r], bk[r]);
        __syncthreads();
        for (int off = 128; off > 0; off >>= 1) {
            if (tid < off) {
                float2 o = red[tid + off];
                float2 m = red[tid];
                if (o.x < m.x || (o.x == m.x && o.y < m.y)) red[tid] = o;
            }
            __syncthreads();
        }
        if (tid == 0) out[1 + rows[r]] = red[0].y;
        __syncthreads();
    }
}

extern "C" void kernel_launch(void* const* d_in, const int* in_sizes, int n_in,
                              void* d_out, int out_size, void* d_ws, size_t ws_size,
                              hipStream_t stream) {
    const float* E = (const float*)d_in[0];
    const float* C = (const float*)d_in[1];
    float* out = (float*)d_out;

    unsigned short* Cfrag = (unsigned short*)d_ws;                 // 512 KB
    float* c2 = (float*)((char*)d_ws + 524288);                    // 4 KB
    int* fcnt = (int*)((char*)d_ws + 524288 + 4096);               // 4 B
    int* flist = fcnt + 1;                                         // MAXF ints

    hipMemsetAsync(d_out, 0, sizeof(float), stream);   // loss accumulator
    hipMemsetAsync(fcnt, 0, sizeof(int), stream);      // refinement counter

    prep_c2_kernel<<<dim3(16), dim3(64), 0, stream>>>(C, c2);
    prep_frag_kernel<<<dim3(128), dim3(256), 0, stream>>>(C, Cfrag);
    fused_mfma_kernel<<<dim3(N_TOTAL / BM), dim3(256), 0, stream>>>(E, Cfrag, c2, out, fcnt, flist);
    refine_kernel<<<dim3(MAXF / 4), dim3(256), 0, stream>>>(E, C, c2, fcnt, flist, out);
}

// Round 4
// 496.364 us; speedup vs baseline: 2.4878x; 1.7556x over previous
//
#include <hip/hip_runtime.h>
#include <stdint.h>

#define D_DIM 128
#define K_DIM 1024
#define BM 64
#define N_TOTAL 262144
#define TAU 0.1f
#define MAXF 16384

typedef __attribute__((ext_vector_type(8))) short short8;
typedef __attribute__((ext_vector_type(4))) float f32x4;

__device__ __forceinline__ unsigned short f2bf(float f) {
    union { float f; uint32_t u; } v; v.f = f;
    uint32_t r = v.u + 0x7fffu + ((v.u >> 16) & 1u);
    return (unsigned short)(r >> 16);
}
__device__ __forceinline__ float bf2f(unsigned short h) {
    union { float f; uint32_t u; } v; v.u = ((uint32_t)h) << 16;
    return v.f;
}

// ---------------------------------------------------------------------------
// prep_c2: c2[k]=|c_k|^2, rounding identical to R2/R3 (4 interleaved chains)
// ---------------------------------------------------------------------------
__global__ void prep_c2_kernel(const float* __restrict__ C,
                               float* __restrict__ c2) {
    int col = blockIdx.x * blockDim.x + threadIdx.x;
    if (col >= K_DIM) return;
    const float4* C4 = (const float4*)(C + (size_t)col * D_DIM);
    float s0 = 0.f, s1 = 0.f, s2 = 0.f, s3 = 0.f;
    #pragma unroll
    for (int dq = 0; dq < 32; ++dq) {
        float4 v = C4[dq];
        s0 = fmaf(v.x, v.x, s0);
        s1 = fmaf(v.y, v.y, s1);
        s2 = fmaf(v.z, v.z, s2);
        s3 = fmaf(v.w, v.w, s3);
    }
    c2[col] = (s0 + s1) + (s2 + s3);
}

// ---------------------------------------------------------------------------
// prep_frag: C[1024][128] fp32 -> B-frag-layout bf16 hi/lo (parallel, coalesced)
// ---------------------------------------------------------------------------
__global__ void prep_frag_kernel(const float* __restrict__ C,
                                 unsigned short* __restrict__ Cfrag) {
    int g = blockIdx.x * blockDim.x + threadIdx.x;   // 0..32767
    int col = g >> 5;
    int dq = g & 31;
    float4 v = ((const float4*)C)[g];
    unsigned short h0 = f2bf(v.x), h1 = f2bf(v.y), h2 = f2bf(v.z), h3 = f2bf(v.w);
    unsigned short l0 = f2bf(v.x - bf2f(h0)), l1 = f2bf(v.y - bf2f(h1));
    unsigned short l2 = f2bf(v.z - bf2f(h2)), l3 = f2bf(v.w - bf2f(h3));
    int ntg = col >> 4;
    int cl = col & 15;
    int d0 = dq << 2;
    int ds = d0 >> 5;
    int lane = (((d0 >> 3) & 3) << 4) | cl;
    int jb = d0 & 7;
    size_t idx = (((size_t)(ntg * 4 + ds) * 64 + lane) * 8 + jb);
    uint2 hv = make_uint2((uint32_t)h0 | ((uint32_t)h1 << 16),
                          (uint32_t)h2 | ((uint32_t)h3 << 16));
    uint2 lv = make_uint2((uint32_t)l0 | ((uint32_t)l1 << 16),
                          (uint32_t)l2 | ((uint32_t)l3 << 16));
    *(uint2*)&Cfrag[idx] = hv;
    *(uint2*)&Cfrag[131072 + idx] = lv;
}

// ---------------------------------------------------------------------------
// fused: bf16x3 MFMA distances + packed-key argmin/2nd-min + sum exp(-d) + loss
// block 256 thr = 4 waves; wave tile 32 rows x 64 cols per kc chunk.
// State packed: key = (bits(d2) & ~1023) | k  (monotone; ties -> lower k).
// __launch_bounds__(256,2): 256-reg budget -> no scratch spill (R2/R3 lesson).
// ---------------------------------------------------------------------------
__global__ __launch_bounds__(256, 2) void fused_mfma_kernel(
        const float* __restrict__ E,
        const unsigned short* __restrict__ Cfrag,
        const float* __restrict__ c2g,
        float* __restrict__ out,
        int* __restrict__ fcnt,
        int* __restrict__ flist)
{
    __shared__ unsigned short Elds[32 * 528];   // 33 KB frag-layout E hi/lo
    __shared__ float c2s[K_DIM];                // 4 KB
    __shared__ float e2s[BM];                   // 256 B
    __shared__ uint32_t mrgk[BM * 2];
    __shared__ uint32_t mrgm[BM * 2];
    __shared__ float    mrgs[BM * 2];

    const int tid = threadIdx.x;
    const int lane = tid & 63;
    const int w = tid >> 6;
    const int Rh = w >> 1;       // row half (32 rows each)
    const int Nh = w & 1;        // col half of each 128-col chunk
    const int q = lane >> 4;
    const int mcol = lane & 15;
    const int row0 = blockIdx.x * BM;

    if (tid < BM) e2s[tid] = 0.f;
    for (int i = tid; i < K_DIM; i += 256) c2s[i] = c2g[i];
    __syncthreads();

    // ---- stage E tile: fp32 -> bf16 hi/lo frag layout; accumulate e2 ----
    {
        const float4* E4 = (const float4*)(E + (size_t)row0 * D_DIM);
        #pragma unroll
        for (int it = 0; it < 8; ++it) {
            int chunk = it * 256 + tid;      // 0..2047
            int r = chunk >> 5;              // row 0..63
            int dq = chunk & 31;
            float4 v = E4[chunk];
            float p = fmaf(v.x, v.x, fmaf(v.y, v.y, fmaf(v.z, v.z, v.w * v.w)));
            atomicAdd(&e2s[r], p);
            unsigned short h0 = f2bf(v.x), h1 = f2bf(v.y), h2 = f2bf(v.z), h3 = f2bf(v.w);
            unsigned short l0 = f2bf(v.x - bf2f(h0)), l1 = f2bf(v.y - bf2f(h1));
            unsigned short l2 = f2bf(v.z - bf2f(h2)), l3 = f2bf(v.w - bf2f(h3));
            int d0 = dq << 2;
            int mt = r >> 4;
            int ds = d0 >> 5;
            int lane_slot = (((d0 >> 3) & 3) << 4) | (r & 15);
            int jb = d0 & 7;
            int segh = (mt * 4 + ds) * 528 + lane_slot * 8 + jb;
            uint2 hv = make_uint2((uint32_t)h0 | ((uint32_t)h1 << 16),
                                  (uint32_t)h2 | ((uint32_t)h3 << 16));
            uint2 lv = make_uint2((uint32_t)l0 | ((uint32_t)l1 << 16),
                                  (uint32_t)l2 | ((uint32_t)l3 << 16));
            *(uint2*)&Elds[segh] = hv;
            *(uint2*)&Elds[16 * 528 + segh] = lv;
        }
    }
    __syncthreads();

    // per-lane e2 for the 8 owned rows: slot s=mi*4+r -> row (Rh*2+mi)*16+q*4+r
    float e2r[8];
    #pragma unroll
    for (int s = 0; s < 8; ++s)
        e2r[s] = e2s[(Rh * 2 + (s >> 2)) * 16 + q * 4 + (s & 3)];

    uint32_t k1v[8], m2v[8];
    float sv[8];
    #pragma unroll
    for (int s = 0; s < 8; ++s) { k1v[s] = 0xFFFFFFFFu; m2v[s] = 0xFFFFFFFFu; sv[s] = 0.f; }

    const short8* Bfrag = (const short8*)Cfrag;   // hi at [0], lo at +16384 (short8 units)

    #pragma unroll 1
    for (int kc = 0; kc < 8; ++kc) {
        f32x4 acc[2][4];
        #pragma unroll
        for (int i = 0; i < 2; ++i)
            #pragma unroll
            for (int j = 0; j < 4; ++j)
                acc[i][j] = (f32x4){0.f, 0.f, 0.f, 0.f};

        #pragma unroll
        for (int ds = 0; ds < 4; ++ds) {
            short8 ah[2], al[2];
            #pragma unroll
            for (int mi = 0; mi < 2; ++mi) {
                int seg = ((Rh * 2 + mi) * 4 + ds) * 528 + lane * 8;
                ah[mi] = *(const short8*)&Elds[seg];
                al[mi] = *(const short8*)&Elds[16 * 528 + seg];
            }
            #pragma unroll
            for (int ni = 0; ni < 4; ++ni) {
                int ntg = kc * 8 + Nh * 4 + ni;
                size_t bidx = ((size_t)ntg * 4 + ds) * 64 + lane;
                short8 bh = Bfrag[bidx];
                short8 bl = Bfrag[16384 + bidx];
                #pragma unroll
                for (int mi = 0; mi < 2; ++mi) {
                    acc[mi][ni] = __builtin_amdgcn_mfma_f32_16x16x32_bf16(al[mi], bh, acc[mi][ni], 0, 0, 0);
                    acc[mi][ni] = __builtin_amdgcn_mfma_f32_16x16x32_bf16(ah[mi], bl, acc[mi][ni], 0, 0, 0);
                    acc[mi][ni] = __builtin_amdgcn_mfma_f32_16x16x32_bf16(ah[mi], bh, acc[mi][ni], 0, 0, 0);
                }
            }
        }
        // fused epilogue for this k-chunk (no barriers in the kc loop)
        #pragma unroll
        for (int ni = 0; ni < 4; ++ni) {
            int kidx = kc * 128 + Nh * 64 + ni * 16 + mcol;
            float c2v = c2s[kidx];
            #pragma unroll
            for (int mi = 0; mi < 2; ++mi) {
                #pragma unroll
                for (int r = 0; r < 4; ++r) {
                    int s = mi * 4 + r;
                    float d2 = fmaf(-2.f, acc[mi][ni][r], e2r[s] + c2v);
                    d2 = fmaxf(d2, 0.f);
                    uint32_t key = (__float_as_uint(d2) & 0xFFFFFC00u) | (uint32_t)kidx;
                    float dist = __builtin_amdgcn_sqrtf(d2);
                    sv[s] += __expf(-dist);
                    uint32_t k1 = k1v[s];
                    m2v[s] = min(m2v[s], max(k1, key));
                    k1v[s] = min(k1, key);
                }
            }
        }
    }

    // ---- merge across the 16 lanes sharing q (cols) ----
    #pragma unroll
    for (int s = 0; s < 8; ++s) {
        #pragma unroll
        for (int off = 1; off < 16; off <<= 1) {
            uint32_t ok1 = __shfl_xor(k1v[s], off);
            uint32_t om2 = __shfl_xor(m2v[s], off);
            float osv = __shfl_xor(sv[s], off);
            m2v[s] = min(min(m2v[s], om2), max(k1v[s], ok1));
            k1v[s] = min(k1v[s], ok1);
            sv[s] += osv;
        }
    }
    if (mcol == 0) {
        #pragma unroll
        for (int s = 0; s < 8; ++s) {
            int row = (Rh * 2 + (s >> 2)) * 16 + q * 4 + (s & 3);
            mrgk[row * 2 + Nh] = k1v[s];
            mrgm[row * 2 + Nh] = m2v[s];
            mrgs[row * 2 + Nh] = sv[s];
        }
    }
    __syncthreads();

    // ---- final per-row merge across the two col-halves; outputs ----
    if (tid < BM) {
        uint32_t ka = mrgk[tid * 2 + 0], kb = mrgk[tid * 2 + 1];
        uint32_t ma = mrgm[tid * 2 + 0], mb = mrgm[tid * 2 + 1];
        float ss = mrgs[tid * 2 + 0] + mrgs[tid * 2 + 1];
        uint32_t k1 = min(ka, kb);
        uint32_t m2 = min(min(ma, mb), max(ka, kb));
        float m1q = __uint_as_float(k1 & 0xFFFFFC00u);
        float m2q = __uint_as_float(m2 & 0xFFFFFC00u);
        int i1 = (int)(k1 & 1023u);
        float lossr = logf(ss) + sqrtf(m1q);   // lse - target
        out[1 + row0 + tid] = (float)i1;
        if (m2q - m1q < TAU) {
            int idx = atomicAdd(fcnt, 1);
            if (idx < MAXF) flist[idx] = row0 + tid;
        }
        float v = lossr;
        #pragma unroll
        for (int off = 32; off > 0; off >>= 1) v += __shfl_down(v, off);
        if (tid == 0) atomicAdd(out, v * (1.0f / (float)N_TOTAL));
    }
}

// ---------------------------------------------------------------------------
// refine: exact fp32 recompute (precise sqrt, first-occurrence argmin) for
// flagged rows. 4 rows per block. UNCHANGED from R2/R3 (rounding-validated).
// ---------------------------------------------------------------------------
__global__ void refine_kernel(const float* __restrict__ E,
                              const float* __restrict__ C,
                              const float* __restrict__ c2g,
                              const int* __restrict__ fcnt,
                              const int* __restrict__ flist,
                              float* __restrict__ out) {
    int cnt = *fcnt;
    if (cnt > MAXF) cnt = MAXF;
    int base = blockIdx.x * 4;
    if (base >= cnt) return;
    int nr = cnt - base;
    if (nr > 4) nr = 4;

    __shared__ float Er[4][D_DIM];
    __shared__ float e2r_[4];
    __shared__ float2 red[256];

    const int tid = threadIdx.x;
    int rows[4];
    #pragma unroll
    for (int r = 0; r < 4; ++r) {
        int rr = r < nr ? r : (nr - 1);
        rows[r] = flist[base + rr];
    }
    for (int i = tid; i < 4 * D_DIM; i += 256) {
        int rr = i >> 7;
        int dd = i & 127;
        Er[rr][dd] = E[(size_t)rows[rr] * D_DIM + dd];
    }
    __syncthreads();
    if (tid < 4) {
        float s = 0.f;
        for (int d = 0; d < D_DIM; ++d) s = fmaf(Er[tid][d], Er[tid][d], s);
        e2r_[tid] = s;
    }
    __syncthreads();

    float bm[4] = {1e30f, 1e30f, 1e30f, 1e30f};
    float bk[4] = {0.f, 0.f, 0.f, 0.f};
    for (int ii = 0; ii < 4; ++ii) {
        int k = ii * 256 + tid;
        float dot0 = 0.f, dot1 = 0.f, dot2 = 0.f, dot3 = 0.f;
        const float4* C4 = (const float4*)(C + (size_t)k * D_DIM);
        for (int dq = 0; dq < 32; ++dq) {
            float4 cv = C4[dq];
            int d0 = dq * 4;
            dot0 = fmaf(Er[0][d0], cv.x, fmaf(Er[0][d0 + 1], cv.y, fmaf(Er[0][d0 + 2], cv.z, fmaf(Er[0][d0 + 3], cv.w, dot0))));
            dot1 = fmaf(Er[1][d0], cv.x, fmaf(Er[1][d0 + 1], cv.y, fmaf(Er[1][d0 + 2], cv.z, fmaf(Er[1][d0 + 3], cv.w, dot1))));
            dot2 = fmaf(Er[2][d0], cv.x, fmaf(Er[2][d0 + 1], cv.y, fmaf(Er[2][d0 + 2], cv.z, fmaf(Er[2][d0 + 3], cv.w, dot2))));
            dot3 = fmaf(Er[3][d0], cv.x, fmaf(Er[3][d0 + 1], cv.y, fmaf(Er[3][d0 + 2], cv.z, fmaf(Er[3][d0 + 3], cv.w, dot3))));
        }
        float c2v = c2g[k];
        float dd[4];
        dd[0] = dot0; dd[1] = dot1; dd[2] = dot2; dd[3] = dot3;
        #pragma unroll
        for (int r = 0; r < 4; ++r) {
            float d2 = (e2r_[r] + c2v) - 2.f * dd[r];
            float dist = sqrtf(fmaxf(d2, 0.f));
            if (dist < bm[r]) { bm[r] = dist; bk[r] = (float)k; }
        }
    }
    for (int r = 0; r < nr; ++r) {
        red[tid] = make_float2(bm[r], bk[r]);
        __syncthreads();
        for (int off = 128; off > 0; off >>= 1) {
            if (tid < off) {
                float2 o = red[tid + off];
                float2 m = red[tid];
                if (o.x < m.x || (o.x == m.x && o.y < m.y)) red[tid] = o;
            }
            __syncthreads();
        }
        if (tid == 0) out[1 + rows[r]] = red[0].y;
        __syncthreads();
    }
}

extern "C" void kernel_launch(void* const* d_in, const int* in_sizes, int n_in,
                              void* d_out, int out_size, void* d_ws, size_t ws_size,
                              hipStream_t stream) {
    const float* E = (const float*)d_in[0];
    const float* C = (const float*)d_in[1];
    float* out = (float*)d_out;

    unsigned short* Cfrag = (unsigned short*)d_ws;                 // 512 KB
    float* c2 = (float*)((char*)d_ws + 524288);                    // 4 KB
    int* fcnt = (int*)((char*)d_ws + 524288 + 4096);               // 4 B
    int* flist = fcnt + 1;                                         // MAXF ints

    hipMemsetAsync(d_out, 0, sizeof(float), stream);   // loss accumulator
    hipMemsetAsync(fcnt, 0, sizeof(int), stream);      // refinement counter

    prep_c2_kernel<<<dim3(16), dim3(64), 0, stream>>>(C, c2);
    prep_frag_kernel<<<dim3(128), dim3(256), 0, stream>>>(C, Cfrag);
    fused_mfma_kernel<<<dim3(N_TOTAL / BM), dim3(256), 0, stream>>>(E, Cfrag, c2, out, fcnt, flist);
    refine_kernel<<<dim3(MAXF / 4), dim3(256), 0, stream>>>(E, C, c2, fcnt, flist, out);
}